// Round 3
// baseline (4919.863 us; speedup 1.0000x reference)
//
#include <hip/hip_runtime.h>
#include <math.h>

typedef __bf16 v8bf __attribute__((ext_vector_type(8)));
typedef float  v16f __attribute__((ext_vector_type(16)));

#define EPS_BN 1e-5f
#define Q_TOTAL 16384
#define N_MEM   262144
#define SLICES  16
#define SLICE_LEN (N_MEM / SLICES)   /* 16384 */
#define CHUNK   256
#define NCHUNKS (SLICE_LEN / CHUNK)  /* 64 */

// async global->LDS, 16B/lane. LDS dest is wave-uniform base + lane*16, so
// the bank swizzle must be folded into the GLOBAL source addresses.
__device__ __forceinline__ void gload_lds16(const void* g, void* l) {
    __builtin_amdgcn_global_load_lds(
        (const __attribute__((address_space(1))) void*)g,
        (__attribute__((address_space(3))) void*)l, 16, 0, 0);
}

// ---------------------------------------------------------------------------
// conv0: [256,1,64,64] -> [256,16,32,32], 3x3 s2 p1 + BN + ReLU
__global__ void conv0_kernel(const float* __restrict__ x,
                             const float* __restrict__ w, const float* __restrict__ bias,
                             const float* __restrict__ gamma, const float* __restrict__ beta,
                             const float* __restrict__ mean, const float* __restrict__ var,
                             float* __restrict__ out) {
    int idx = blockIdx.x * 256 + threadIdx.x;
    int xo = idx & 31, yo = (idx >> 5) & 31, c = (idx >> 10) & 15, b = idx >> 14;
    const float* xp = x + (size_t)b * 4096;
    const float* wc = w + c * 9;
    float acc = 0.f;
#pragma unroll
    for (int dy = 0; dy < 3; ++dy) {
        int iy = 2 * yo + dy - 1;
        if (iy < 0) continue;
#pragma unroll
        for (int dx = 0; dx < 3; ++dx) {
            int ix = 2 * xo + dx - 1;
            if (ix < 0) continue;
            acc += wc[dy * 3 + dx] * xp[iy * 64 + ix];
        }
    }
    acc += bias[c];
    float sc = gamma[c] * rsqrtf(var[c] + EPS_BN);
    float v  = (acc - mean[c]) * sc + beta[c];
    out[idx] = fmaxf(v, 0.f);
}

// ---------------------------------------------------------------------------
// conv1: [256,16,32,32] -> [256,32,16,16]. LDS-staged per (image, 8-ch group).
__global__ void conv1_kernel(const float* __restrict__ in,
                             const float* __restrict__ w, const float* __restrict__ bias,
                             const float* __restrict__ gamma, const float* __restrict__ beta,
                             const float* __restrict__ mean, const float* __restrict__ var,
                             float* __restrict__ out) {
    __shared__ float in_s[16384];
    __shared__ float w_s[1152];
    __shared__ float sc_s[8], sh_s[8];
    int b = blockIdx.x >> 2, cg = blockIdx.x & 3;
    int t = threadIdx.x;
    const float4* ip4 = (const float4*)(in + (size_t)b * 16384);
    float4* is4 = (float4*)in_s;
    for (int i = t; i < 4096; i += 256) is4[i] = ip4[i];
    for (int i = t; i < 1152; i += 256) w_s[i] = w[cg * 1152 + i];
    if (t < 8) {
        int c = cg * 8 + t;
        float sc = gamma[c] * rsqrtf(var[c] + EPS_BN);
        sc_s[t] = sc;
        sh_s[t] = (bias[c] - mean[c]) * sc + beta[c];
    }
    __syncthreads();
    int xo = t & 15, yo = t >> 4;
    float acc[8];
#pragma unroll
    for (int c = 0; c < 8; ++c) acc[c] = 0.f;
    int iy0 = 2 * yo - 1, ix0 = 2 * xo - 1;
    for (int ci = 0; ci < 16; ++ci) {
        const float* base = in_s + ci * 1024;
        float r[9];
#pragma unroll
        for (int dy = 0; dy < 3; ++dy) {
            int iy = iy0 + dy;
            int iyc = iy < 0 ? 0 : iy;
#pragma unroll
            for (int dx = 0; dx < 3; ++dx) {
                int ix = ix0 + dx;
                int ixc = ix < 0 ? 0 : ix;
                float v = base[iyc * 32 + ixc];
                r[dy * 3 + dx] = (iy >= 0 && ix >= 0) ? v : 0.f;
            }
        }
#pragma unroll
        for (int c = 0; c < 8; ++c) {
            const float* wp = w_s + (c * 16 + ci) * 9;
#pragma unroll
            for (int k = 0; k < 9; ++k) acc[c] = fmaf(wp[k], r[k], acc[c]);
        }
    }
#pragma unroll
    for (int c = 0; c < 8; ++c) {
        float v = fmaf(acc[c], sc_s[c], sh_s[c]);
        out[((size_t)(b * 32 + cg * 8 + c) * 16 + yo) * 16 + xo] = fmaxf(v, 0.f);
    }
}

// ---------------------------------------------------------------------------
// conv2: [256,32,16,16] -> [256,64,8,8]. LDS-staged per (image, 16-ch group).
__global__ void conv2_kernel(const float* __restrict__ in,
                             const float* __restrict__ w, const float* __restrict__ bias,
                             const float* __restrict__ gamma, const float* __restrict__ beta,
                             const float* __restrict__ mean, const float* __restrict__ var,
                             float* __restrict__ out) {
    __shared__ float in_s[8192];
    __shared__ float w_s[4608];
    __shared__ float sc_s[16], sh_s[16];
    int b = blockIdx.x >> 2, cg = blockIdx.x & 3;
    int t = threadIdx.x;
    const float4* ip4 = (const float4*)(in + (size_t)b * 8192);
    float4* is4 = (float4*)in_s;
    for (int i = t; i < 2048; i += 256) is4[i] = ip4[i];
    for (int i = t; i < 4608; i += 256) w_s[i] = w[cg * 4608 + i];
    if (t < 16) {
        int c = cg * 16 + t;
        float sc = gamma[c] * rsqrtf(var[c] + EPS_BN);
        sc_s[t] = sc;
        sh_s[t] = (bias[c] - mean[c]) * sc + beta[c];
    }
    __syncthreads();
    int xo = t & 7, yo = (t >> 3) & 7, cs = t >> 6;
    float acc[4];
#pragma unroll
    for (int l = 0; l < 4; ++l) acc[l] = 0.f;
    int iy0 = 2 * yo - 1, ix0 = 2 * xo - 1;
    for (int ci = 0; ci < 32; ++ci) {
        const float* base = in_s + ci * 256;
        float r[9];
#pragma unroll
        for (int dy = 0; dy < 3; ++dy) {
            int iy = iy0 + dy;
            int iyc = iy < 0 ? 0 : iy;
#pragma unroll
            for (int dx = 0; dx < 3; ++dx) {
                int ix = ix0 + dx;
                int ixc = ix < 0 ? 0 : ix;
                float v = base[iyc * 16 + ixc];
                r[dy * 3 + dx] = (iy >= 0 && ix >= 0) ? v : 0.f;
            }
        }
#pragma unroll
        for (int l = 0; l < 4; ++l) {
            const float* wp = w_s + ((cs * 4 + l) * 32 + ci) * 9;
#pragma unroll
            for (int k = 0; k < 9; ++k) acc[l] = fmaf(wp[k], r[k], acc[l]);
        }
    }
#pragma unroll
    for (int l = 0; l < 4; ++l) {
        int c = cg * 16 + cs * 4 + l;
        float v = fmaf(acc[l], sc_s[cs * 4 + l], sh_s[cs * 4 + l]);
        out[((size_t)(b * 64 + c) * 8 + yo) * 8 + xo] = fmaxf(v, 0.f);
    }
}

// ---------------------------------------------------------------------------
// qnorm: y2 [256,64,8,8] -> transpose -> L2 normalize -> bf16; qsq from the
// bf16-rounded values. Also initializes mind2 (+inf) for the dist kernel.
__global__ void qnorm_kernel(const float* __restrict__ y2,
                             __bf16* __restrict__ q, float* __restrict__ qsq,
                             unsigned int* __restrict__ mind2) {
    __shared__ float  L1s[4096];
    __shared__ __bf16 L2s[4096];
    int b = blockIdx.x, t = threadIdx.x;          // 64 threads
    mind2[b * 64 + t] = 0x7f800000u;              // +inf init
    const float* src = y2 + (size_t)b * 4096;
    for (int i = t; i < 4096; i += 64) L1s[i] = src[i];
    __syncthreads();
    int p = t;
    float ss = 0.f;
    for (int d = 0; d < 64; ++d) { float v = L1s[d * 64 + p]; ss += v * v; }
    float inv = 1.f / fmaxf(sqrtf(ss), 1e-12f);
    float q2 = 0.f;
    for (int d = 0; d < 64; ++d) {
        float v = L1s[d * 64 + p] * inv;
        __bf16 bv = (__bf16)v;
        L2s[p * 64 + d] = bv;
        float fb = (float)bv;
        q2 += fb * fb;
    }
    qsq[b * 64 + p] = q2;
    __syncthreads();
    for (int p2 = 0; p2 < 64; ++p2)
        q[((size_t)(b * 64 + p2)) * 64 + t] = L2s[p2 * 64 + t];
}

// mbnorm: normalize bank rows, pack bf16, msq from bf16-rounded values.
__global__ void mbnorm_kernel(const float* __restrict__ mb,
                              __bf16* __restrict__ mbbf, float* __restrict__ msq) {
    int row  = blockIdx.x * 4 + (threadIdx.x >> 6);
    int lane = threadIdx.x & 63;
    float v = mb[(size_t)row * 64 + lane];
    float ss = v * v;
#pragma unroll
    for (int o = 1; o < 64; o <<= 1) ss += __shfl_xor(ss, o, 64);
    float inv = 1.f / fmaxf(sqrtf(ss), 1e-12f);
    __bf16 bv = (__bf16)(v * inv);
    mbbf[(size_t)row * 64 + lane] = bv;
    float fb = (float)bv;
    float s2 = fb * fb;
#pragma unroll
    for (int o = 1; o < 64; o <<= 1) s2 += __shfl_xor(s2, o, 64);
    if (lane == 0) msq[row] = s2;
}

// ---------------------------------------------------------------------------
// dist v3: 32x32x16 bf16 MFMA, msq folded into C-init (acc = dot - msq/2).
// mt=4 strips/wave (BM=512/block) -> each B frag feeds 4 strips (halves LDS
// read per MFMA vs v2). CHUNK=256 rows (32 KB) double-buffered: per-chunk
// compute = 512 MFMA/block (~4096 CU-cyc) >> load latency (~900 cyc), so the
// vmcnt(0) drain at the barrier is issued long after the prefetch and is
// nearly free (v2's stall: chunk time ~ latency). Grid 32x16 = 512 blocks =
// exactly 2 resident/CU (LDS 64 KB, VGPR<=256 via launch_bounds), no tail.
__global__ __launch_bounds__(256, 2)
void dist_kernel(const __bf16* __restrict__ q, const float* __restrict__ qsq,
                 const __bf16* __restrict__ mb, const float* __restrict__ msq,
                 unsigned int* __restrict__ mind2) {
    __shared__ __align__(16) __bf16 Bs[2][CHUNK * 64];   // 2 x 32 KB
    const int t = threadIdx.x;
    const int wave = t >> 6, lane = t & 63;
    const int n32 = lane & 31, half = lane >> 5;
    const int mbase = blockIdx.x * 512 + wave * 128;
    const int slice = blockIdx.y;

    // A fragments: 4 strips x 4 ksteps, register resident (64 VGPR).
    v8bf a[4][4];
#pragma unroll
    for (int s = 0; s < 4; ++s)
#pragma unroll
        for (int ks = 0; ks < 4; ++ks)
            a[s][ks] = *(const v8bf*)(q + (size_t)(mbase + s * 32 + n32) * 64
                                        + ks * 16 + half * 8);

    float tmax[4][16];
#pragma unroll
    for (int s = 0; s < 4; ++s)
#pragma unroll
        for (int r = 0; r < 16; ++r) tmax[s][r] = -3.0e38f;

    // staging: 8 granule-sets of 256 x 16B per chunk; XOR(col^row&7) swizzle
    // folded into the global source address. Granule g=j*256+t holds row g>>3,
    // 16B-position g&7 (contains global column (g&7)^(row&7)).
    const __bf16* gbase = mb + (size_t)slice * SLICE_LEN * 64;
    const __bf16* src[8];
    int dofs[8];
#pragma unroll
    for (int j = 0; j < 8; ++j) {
        int g = j * 256 + t, r = g >> 3, c = (g & 7) ^ (r & 7);
        src[j]  = gbase + r * 64 + c * 8;
        dofs[j] = j * 4096 + wave * 1024;
    }
    // prologue: chunk 0 -> buf 0
#pragma unroll
    for (int j = 0; j < 8; ++j) {
        gload_lds16(src[j], (char*)Bs[0] + dofs[j]);
        src[j] += CHUNK * 64;
    }

    const float* msbase = msq + slice * SLICE_LEN + n32;

    auto step = [&](const char* bp, char* pdst, bool pref, int nbofs) {
        __syncthreads();          // drains staging (vmcnt0) + sync
        if (pref) {
#pragma unroll
            for (int j = 0; j < 8; ++j) {
                gload_lds16(src[j], pdst + dofs[j]);
                src[j] += CHUNK * 64;
            }
        }
#pragma unroll
        for (int nt = 0; nt < 8; ++nt) {
            float ms = msbase[nbofs + nt * 32];
            float cinit = -0.5f * ms;
            const int n = nt * 32 + n32;
            const int rowb = n * 128;
            const int sw = (n & 7) << 4;
            v8bf bf[4];
#pragma unroll
            for (int ks = 0; ks < 4; ++ks)
                bf[ks] = *(const v8bf*)(bp + rowb + (((ks * 2 + half) << 4) ^ sw));
            // strips in pairs: caps in-flight accumulators at 2x16
#pragma unroll
            for (int sg = 0; sg < 2; ++sg) {
                v16f C;
#pragma unroll
                for (int r = 0; r < 16; ++r) C[r] = cinit;
                v16f a0 = __builtin_amdgcn_mfma_f32_32x32x16_bf16(a[2 * sg][0],     bf[0], C, 0, 0, 0);
                v16f a1 = __builtin_amdgcn_mfma_f32_32x32x16_bf16(a[2 * sg + 1][0], bf[0], C, 0, 0, 0);
#pragma unroll
                for (int ks = 1; ks < 4; ++ks) {
                    a0 = __builtin_amdgcn_mfma_f32_32x32x16_bf16(a[2 * sg][ks],     bf[ks], a0, 0, 0, 0);
                    a1 = __builtin_amdgcn_mfma_f32_32x32x16_bf16(a[2 * sg + 1][ks], bf[ks], a1, 0, 0, 0);
                }
#pragma unroll
                for (int r = 0; r < 16; ++r) {
                    tmax[2 * sg][r]     = fmaxf(tmax[2 * sg][r],     a0[r]);
                    tmax[2 * sg + 1][r] = fmaxf(tmax[2 * sg + 1][r], a1[r]);
                }
            }
        }
    };

    for (int ch = 0; ch < NCHUNKS; ch += 2) {
        step((const char*)Bs[0], (char*)Bs[1], true, ch * CHUNK);
        step((const char*)Bs[1], (char*)Bs[0], ch + 2 < NCHUNKS, (ch + 1) * CHUNK);
    }

    // min_n(msq - 2 dot) = -2 * max_n(dot - msq/2) = -2 * tmax
#pragma unroll
    for (int s = 0; s < 4; ++s)
#pragma unroll
        for (int r = 0; r < 16; ++r) {
            float v = tmax[s][r];
            v = fmaxf(v, __shfl_xor(v, 1, 64));
            v = fmaxf(v, __shfl_xor(v, 2, 64));
            v = fmaxf(v, __shfl_xor(v, 4, 64));
            v = fmaxf(v, __shfl_xor(v, 8, 64));
            v = fmaxf(v, __shfl_xor(v, 16, 64));
            tmax[s][r] = v;
        }
    if (n32 == 0) {
#pragma unroll
        for (int s = 0; s < 4; ++s)
#pragma unroll
            for (int r = 0; r < 16; ++r) {
                int row = (r & 3) + 8 * (r >> 2) + 4 * half;  // C/D row map
                int m = mbase + s * 32 + row;
                float dd = fmaxf(qsq[m] - 2.0f * tmax[s][r], 0.f);
                atomicMin(mind2 + m, __float_as_uint(dd));
            }
    }
}

// finalize: out[b] = max_p sqrt(mind2[b*64+p])
__global__ void finalize_kernel(const unsigned int* __restrict__ mind2,
                                float* __restrict__ out) {
    int b = blockIdx.x, l = threadIdx.x;
    float v = __uint_as_float(mind2[b * 64 + l]);
    float d = sqrtf(fmaxf(v, 0.f));
#pragma unroll
    for (int o = 1; o < 64; o <<= 1) d = fmaxf(d, __shfl_xor(d, o, 64));
    if (l == 0) out[b] = d;
}

// ---------------------------------------------------------------------------
extern "C" void kernel_launch(void* const* d_in, const int* in_sizes, int n_in,
                              void* d_out, int out_size, void* d_ws, size_t ws_size,
                              hipStream_t stream) {
    (void)in_sizes; (void)n_in; (void)out_size; (void)ws_size;
    const float* x     = (const float*)d_in[0];
    const float* mbank = (const float*)d_in[1];
    const float* w0 = (const float*)d_in[2],  *b0 = (const float*)d_in[3];
    const float* g0 = (const float*)d_in[4],  *be0 = (const float*)d_in[5];
    const float* mn0 = (const float*)d_in[6], *vr0 = (const float*)d_in[7];
    const float* w1 = (const float*)d_in[8],  *b1 = (const float*)d_in[9];
    const float* g1 = (const float*)d_in[10], *be1 = (const float*)d_in[11];
    const float* mn1 = (const float*)d_in[12], *vr1 = (const float*)d_in[13];
    const float* w2 = (const float*)d_in[14], *b2 = (const float*)d_in[15];
    const float* g2 = (const float*)d_in[16], *be2 = (const float*)d_in[17];
    const float* mn2 = (const float*)d_in[18], *vr2 = (const float*)d_in[19];

    char* ws = (char*)d_ws;
    float*        y0    = (float*)(ws + 0);              // 16.78 MB
    float*        y1    = (float*)(ws + 16777216);       // 8.39 MB
    float*        y2    = (float*)(ws + 25165824);       // 4.19 MB
    __bf16*       qbf   = (__bf16*)(ws + 29360128);      // 2.10 MB
    float*        qsq   = (float*)(ws + 31457280);       // 64 KB
    __bf16*       mbbf  = (__bf16*)(ws + 31522816);      // 33.55 MB
    float*        msq   = (float*)(ws + 65077248);       // 1.05 MB
    unsigned int* mind2 = (unsigned int*)(ws + 66125824);// 64 KB

    conv0_kernel<<<16384, 256, 0, stream>>>(x, w0, b0, g0, be0, mn0, vr0, y0);
    conv1_kernel<<<1024, 256, 0, stream>>>(y0, w1, b1, g1, be1, mn1, vr1, y1);
    conv2_kernel<<<1024, 256, 0, stream>>>(y1, w2, b2, g2, be2, mn2, vr2, y2);
    qnorm_kernel<<<256, 64, 0, stream>>>(y2, qbf, qsq, mind2);
    mbnorm_kernel<<<65536, 256, 0, stream>>>(mbank, mbbf, msq);
    dist_kernel<<<dim3(32, SLICES), 256, 0, stream>>>(qbf, qsq, mbbf, msq, mind2);
    finalize_kernel<<<256, 64, 0, stream>>>(mind2, (float*)d_out);
}

// Round 4
// 1632.861 us; speedup vs baseline: 3.0130x; 3.0130x over previous
//
#include <hip/hip_runtime.h>
#include <math.h>

typedef __bf16 v8bf __attribute__((ext_vector_type(8)));
typedef float  v16f __attribute__((ext_vector_type(16)));

#define EPS_BN 1e-5f
#define Q_TOTAL 16384
#define N_MEM   262144
#define SLICES  16
#define SLICE_LEN (N_MEM / SLICES)   /* 16384 */
#define CHUNK   256
#define NCHUNKS (SLICE_LEN / CHUNK)  /* 64 */

// async global->LDS, 16B/lane. LDS dest is wave-uniform base + lane*16, so
// the bank swizzle must be folded into the GLOBAL source addresses.
__device__ __forceinline__ void gload_lds16(const void* g, void* l) {
    __builtin_amdgcn_global_load_lds(
        (const __attribute__((address_space(1))) void*)g,
        (__attribute__((address_space(3))) void*)l, 16, 0, 0);
}

// ---------------------------------------------------------------------------
// conv0: [256,1,64,64] -> [256,16,32,32], 3x3 s2 p1 + BN + ReLU
__global__ void conv0_kernel(const float* __restrict__ x,
                             const float* __restrict__ w, const float* __restrict__ bias,
                             const float* __restrict__ gamma, const float* __restrict__ beta,
                             const float* __restrict__ mean, const float* __restrict__ var,
                             float* __restrict__ out) {
    int idx = blockIdx.x * 256 + threadIdx.x;
    int xo = idx & 31, yo = (idx >> 5) & 31, c = (idx >> 10) & 15, b = idx >> 14;
    const float* xp = x + (size_t)b * 4096;
    const float* wc = w + c * 9;
    float acc = 0.f;
#pragma unroll
    for (int dy = 0; dy < 3; ++dy) {
        int iy = 2 * yo + dy - 1;
        if (iy < 0) continue;
#pragma unroll
        for (int dx = 0; dx < 3; ++dx) {
            int ix = 2 * xo + dx - 1;
            if (ix < 0) continue;
            acc += wc[dy * 3 + dx] * xp[iy * 64 + ix];
        }
    }
    acc += bias[c];
    float sc = gamma[c] * rsqrtf(var[c] + EPS_BN);
    float v  = (acc - mean[c]) * sc + beta[c];
    out[idx] = fmaxf(v, 0.f);
}

// ---------------------------------------------------------------------------
// conv1: [256,16,32,32] -> [256,32,16,16]. LDS-staged per (image, 8-ch group).
__global__ void conv1_kernel(const float* __restrict__ in,
                             const float* __restrict__ w, const float* __restrict__ bias,
                             const float* __restrict__ gamma, const float* __restrict__ beta,
                             const float* __restrict__ mean, const float* __restrict__ var,
                             float* __restrict__ out) {
    __shared__ float in_s[16384];
    __shared__ float w_s[1152];
    __shared__ float sc_s[8], sh_s[8];
    int b = blockIdx.x >> 2, cg = blockIdx.x & 3;
    int t = threadIdx.x;
    const float4* ip4 = (const float4*)(in + (size_t)b * 16384);
    float4* is4 = (float4*)in_s;
    for (int i = t; i < 4096; i += 256) is4[i] = ip4[i];
    for (int i = t; i < 1152; i += 256) w_s[i] = w[cg * 1152 + i];
    if (t < 8) {
        int c = cg * 8 + t;
        float sc = gamma[c] * rsqrtf(var[c] + EPS_BN);
        sc_s[t] = sc;
        sh_s[t] = (bias[c] - mean[c]) * sc + beta[c];
    }
    __syncthreads();
    int xo = t & 15, yo = t >> 4;
    float acc[8];
#pragma unroll
    for (int c = 0; c < 8; ++c) acc[c] = 0.f;
    int iy0 = 2 * yo - 1, ix0 = 2 * xo - 1;
    for (int ci = 0; ci < 16; ++ci) {
        const float* base = in_s + ci * 1024;
        float r[9];
#pragma unroll
        for (int dy = 0; dy < 3; ++dy) {
            int iy = iy0 + dy;
            int iyc = iy < 0 ? 0 : iy;
#pragma unroll
            for (int dx = 0; dx < 3; ++dx) {
                int ix = ix0 + dx;
                int ixc = ix < 0 ? 0 : ix;
                float v = base[iyc * 32 + ixc];
                r[dy * 3 + dx] = (iy >= 0 && ix >= 0) ? v : 0.f;
            }
        }
#pragma unroll
        for (int c = 0; c < 8; ++c) {
            const float* wp = w_s + (c * 16 + ci) * 9;
#pragma unroll
            for (int k = 0; k < 9; ++k) acc[c] = fmaf(wp[k], r[k], acc[c]);
        }
    }
#pragma unroll
    for (int c = 0; c < 8; ++c) {
        float v = fmaf(acc[c], sc_s[c], sh_s[c]);
        out[((size_t)(b * 32 + cg * 8 + c) * 16 + yo) * 16 + xo] = fmaxf(v, 0.f);
    }
}

// ---------------------------------------------------------------------------
// conv2: [256,32,16,16] -> [256,64,8,8]. LDS-staged per (image, 16-ch group).
__global__ void conv2_kernel(const float* __restrict__ in,
                             const float* __restrict__ w, const float* __restrict__ bias,
                             const float* __restrict__ gamma, const float* __restrict__ beta,
                             const float* __restrict__ mean, const float* __restrict__ var,
                             float* __restrict__ out) {
    __shared__ float in_s[8192];
    __shared__ float w_s[4608];
    __shared__ float sc_s[16], sh_s[16];
    int b = blockIdx.x >> 2, cg = blockIdx.x & 3;
    int t = threadIdx.x;
    const float4* ip4 = (const float4*)(in + (size_t)b * 8192);
    float4* is4 = (float4*)in_s;
    for (int i = t; i < 2048; i += 256) is4[i] = ip4[i];
    for (int i = t; i < 4608; i += 256) w_s[i] = w[cg * 4608 + i];
    if (t < 16) {
        int c = cg * 16 + t;
        float sc = gamma[c] * rsqrtf(var[c] + EPS_BN);
        sc_s[t] = sc;
        sh_s[t] = (bias[c] - mean[c]) * sc + beta[c];
    }
    __syncthreads();
    int xo = t & 7, yo = (t >> 3) & 7, cs = t >> 6;
    float acc[4];
#pragma unroll
    for (int l = 0; l < 4; ++l) acc[l] = 0.f;
    int iy0 = 2 * yo - 1, ix0 = 2 * xo - 1;
    for (int ci = 0; ci < 32; ++ci) {
        const float* base = in_s + ci * 256;
        float r[9];
#pragma unroll
        for (int dy = 0; dy < 3; ++dy) {
            int iy = iy0 + dy;
            int iyc = iy < 0 ? 0 : iy;
#pragma unroll
            for (int dx = 0; dx < 3; ++dx) {
                int ix = ix0 + dx;
                int ixc = ix < 0 ? 0 : ix;
                float v = base[iyc * 16 + ixc];
                r[dy * 3 + dx] = (iy >= 0 && ix >= 0) ? v : 0.f;
            }
        }
#pragma unroll
        for (int l = 0; l < 4; ++l) {
            const float* wp = w_s + ((cs * 4 + l) * 32 + ci) * 9;
#pragma unroll
            for (int k = 0; k < 9; ++k) acc[l] = fmaf(wp[k], r[k], acc[l]);
        }
    }
#pragma unroll
    for (int l = 0; l < 4; ++l) {
        int c = cg * 16 + cs * 4 + l;
        float v = fmaf(acc[l], sc_s[cs * 4 + l], sh_s[cs * 4 + l]);
        out[((size_t)(b * 64 + c) * 8 + yo) * 8 + xo] = fmaxf(v, 0.f);
    }
}

// ---------------------------------------------------------------------------
// qnorm: y2 [256,64,8,8] -> transpose -> L2 normalize -> bf16; qsq from the
// bf16-rounded values. Also initializes mind2 (+inf) for the dist kernel.
__global__ void qnorm_kernel(const float* __restrict__ y2,
                             __bf16* __restrict__ q, float* __restrict__ qsq,
                             unsigned int* __restrict__ mind2) {
    __shared__ float  L1s[4096];
    __shared__ __bf16 L2s[4096];
    int b = blockIdx.x, t = threadIdx.x;          // 64 threads
    mind2[b * 64 + t] = 0x7f800000u;              // +inf init
    const float* src = y2 + (size_t)b * 4096;
    for (int i = t; i < 4096; i += 64) L1s[i] = src[i];
    __syncthreads();
    int p = t;
    float ss = 0.f;
    for (int d = 0; d < 64; ++d) { float v = L1s[d * 64 + p]; ss += v * v; }
    float inv = 1.f / fmaxf(sqrtf(ss), 1e-12f);
    float q2 = 0.f;
    for (int d = 0; d < 64; ++d) {
        float v = L1s[d * 64 + p] * inv;
        __bf16 bv = (__bf16)v;
        L2s[p * 64 + d] = bv;
        float fb = (float)bv;
        q2 += fb * fb;
    }
    qsq[b * 64 + p] = q2;
    __syncthreads();
    for (int p2 = 0; p2 < 64; ++p2)
        q[((size_t)(b * 64 + p2)) * 64 + t] = L2s[p2 * 64 + t];
}

// mbnorm: normalize bank rows, pack bf16, msq from bf16-rounded values.
__global__ void mbnorm_kernel(const float* __restrict__ mb,
                              __bf16* __restrict__ mbbf, float* __restrict__ msq) {
    int row  = blockIdx.x * 4 + (threadIdx.x >> 6);
    int lane = threadIdx.x & 63;
    float v = mb[(size_t)row * 64 + lane];
    float ss = v * v;
#pragma unroll
    for (int o = 1; o < 64; o <<= 1) ss += __shfl_xor(ss, o, 64);
    float inv = 1.f / fmaxf(sqrtf(ss), 1e-12f);
    __bf16 bv = (__bf16)(v * inv);
    mbbf[(size_t)row * 64 + lane] = bv;
    float fb = (float)bv;
    float s2 = fb * fb;
#pragma unroll
    for (int o = 1; o < 64; o <<= 1) s2 += __shfl_xor(s2, o, 64);
    if (lane == 0) msq[row] = s2;
}

// ---------------------------------------------------------------------------
// dist v4: mt=4 strips (BM=512/block), CHUNK=256 double-buffered, same
// pipeline as v3 BUT register-pressure-fixed (v3 spilled: 14 GB scratch):
//  - no launch_bounds min-waves cap (v3's (256,2) capped unified regs at 256
//    while ~370 were live -> full accumulator spill each chunk)
//  - ONE staging pointer (granule set j = src0 + j*4096B; XOR swizzle is
//    j-invariant since 32 rows/set ≡ 0 mod 8) instead of 8 pointers
//  - in-place C-init (acc[r]=cinit, chained MFMA) -> 32 in-flight regs
//  - msq register double-buffer: next chunk's 8 values prefetched during
//    current chunk (v2/v3 loaded them at first-use: ~900cyc stall per chunk)
// Live regs/lane ~195: a[4][4]=64, tmax[4][16]=64, inflight 32, bf 16, ptrs+misc ~20.
__global__ __launch_bounds__(256)
void dist_kernel(const __bf16* __restrict__ q, const float* __restrict__ qsq,
                 const __bf16* __restrict__ mb, const float* __restrict__ msq,
                 unsigned int* __restrict__ mind2) {
    __shared__ __align__(16) __bf16 Bs[2][CHUNK * 64];   // 2 x 32 KB
    const int t = threadIdx.x;
    const int wave = t >> 6, lane = t & 63;
    const int n32 = lane & 31, half = lane >> 5;
    const int mbase = blockIdx.x * 512 + wave * 128;
    const int slice = blockIdx.y;

    // A fragments: 4 strips x 4 ksteps, register resident (64 VGPR).
    v8bf a[4][4];
#pragma unroll
    for (int s = 0; s < 4; ++s)
#pragma unroll
        for (int ks = 0; ks < 4; ++ks)
            a[s][ks] = *(const v8bf*)(q + (size_t)(mbase + s * 32 + n32) * 64
                                        + ks * 16 + half * 8);

    float tmax[4][16];
#pragma unroll
    for (int s = 0; s < 4; ++s)
#pragma unroll
        for (int r = 0; r < 16; ++r) tmax[s][r] = -3.0e38f;

    // single staging pointer: granule g=j*256+t -> row g>>3, pos (g&7)^(row&7).
    // Since (j*256)>>3 = j*32 ≡ 0 (mod 8), the swizzled position is
    // j-independent: set j reads from src0 + j*4096 bytes.
    const int r0 = t >> 3, c0 = (t & 7) ^ (r0 & 7);
    const __bf16* gp = mb + (size_t)slice * SLICE_LEN * 64 + r0 * 64 + c0 * 8;
    const int wbase = wave * 1024;

    // prologue: chunk 0 -> buf 0 (gp ends exactly at chunk 1's start)
#pragma unroll
    for (int j = 0; j < 8; ++j) {
        gload_lds16(gp, (char*)Bs[0] + j * 4096 + wbase);
        gp += 2048;
    }

    // msq double-buffer: msf = current chunk, prefetch next during compute
    const float* msp = msq + slice * SLICE_LEN + n32;
    float msf[8];
#pragma unroll
    for (int j = 0; j < 8; ++j) msf[j] = msp[j * 32];
    msp += CHUNK;

    auto step = [&](const char* bp, char* pdst, bool more) {
        __syncthreads();          // drains staging (vmcnt0) + sync
        if (more) {
#pragma unroll
            for (int j = 0; j < 8; ++j) {
                gload_lds16(gp, pdst + j * 4096 + wbase);
                gp += 2048;
            }
        }
        float msn[8];
        if (more) {
#pragma unroll
            for (int j = 0; j < 8; ++j) msn[j] = msp[j * 32];
            msp += CHUNK;
        }
#pragma unroll
        for (int nt = 0; nt < 8; ++nt) {
            const float cinit = -0.5f * msf[nt];
            const int n = nt * 32 + n32;
            const int rowb = n * 128;
            const int sw = (n & 7) << 4;
            v8bf bf[4];
#pragma unroll
            for (int ks = 0; ks < 4; ++ks)
                bf[ks] = *(const v8bf*)(bp + rowb + (((ks * 2 + half) << 4) ^ sw));
            // strips in pairs (ILP), accumulators init'd in place
#pragma unroll
            for (int sg = 0; sg < 2; ++sg) {
                v16f a0, a1;
#pragma unroll
                for (int r = 0; r < 16; ++r) { a0[r] = cinit; a1[r] = cinit; }
#pragma unroll
                for (int ks = 0; ks < 4; ++ks) {
                    a0 = __builtin_amdgcn_mfma_f32_32x32x16_bf16(a[2 * sg][ks],     bf[ks], a0, 0, 0, 0);
                    a1 = __builtin_amdgcn_mfma_f32_32x32x16_bf16(a[2 * sg + 1][ks], bf[ks], a1, 0, 0, 0);
                }
#pragma unroll
                for (int r = 0; r < 16; ++r) {
                    tmax[2 * sg][r]     = fmaxf(tmax[2 * sg][r],     a0[r]);
                    tmax[2 * sg + 1][r] = fmaxf(tmax[2 * sg + 1][r], a1[r]);
                }
            }
        }
        if (more) {
#pragma unroll
            for (int j = 0; j < 8; ++j) msf[j] = msn[j];
        }
    };

    for (int ch = 0; ch < NCHUNKS; ch += 2) {
        step((const char*)Bs[0], (char*)Bs[1], ch + 1 < NCHUNKS);
        step((const char*)Bs[1], (char*)Bs[0], ch + 2 < NCHUNKS);
    }

    // min_n(msq - 2 dot) = -2 * max_n(dot - msq/2) = -2 * tmax
#pragma unroll
    for (int s = 0; s < 4; ++s)
#pragma unroll
        for (int r = 0; r < 16; ++r) {
            float v = tmax[s][r];
            v = fmaxf(v, __shfl_xor(v, 1, 64));
            v = fmaxf(v, __shfl_xor(v, 2, 64));
            v = fmaxf(v, __shfl_xor(v, 4, 64));
            v = fmaxf(v, __shfl_xor(v, 8, 64));
            v = fmaxf(v, __shfl_xor(v, 16, 64));
            tmax[s][r] = v;
        }
    if (n32 == 0) {
#pragma unroll
        for (int s = 0; s < 4; ++s)
#pragma unroll
            for (int r = 0; r < 16; ++r) {
                int row = (r & 3) + 8 * (r >> 2) + 4 * half;  // C/D row map
                int m = mbase + s * 32 + row;
                float dd = fmaxf(qsq[m] - 2.0f * tmax[s][r], 0.f);
                atomicMin(mind2 + m, __float_as_uint(dd));
            }
    }
}

// finalize: out[b] = max_p sqrt(mind2[b*64+p])
__global__ void finalize_kernel(const unsigned int* __restrict__ mind2,
                                float* __restrict__ out) {
    int b = blockIdx.x, l = threadIdx.x;
    float v = __uint_as_float(mind2[b * 64 + l]);
    float d = sqrtf(fmaxf(v, 0.f));
#pragma unroll
    for (int o = 1; o < 64; o <<= 1) d = fmaxf(d, __shfl_xor(d, o, 64));
    if (l == 0) out[b] = d;
}

// ---------------------------------------------------------------------------
extern "C" void kernel_launch(void* const* d_in, const int* in_sizes, int n_in,
                              void* d_out, int out_size, void* d_ws, size_t ws_size,
                              hipStream_t stream) {
    (void)in_sizes; (void)n_in; (void)out_size; (void)ws_size;
    const float* x     = (const float*)d_in[0];
    const float* mbank = (const float*)d_in[1];
    const float* w0 = (const float*)d_in[2],  *b0 = (const float*)d_in[3];
    const float* g0 = (const float*)d_in[4],  *be0 = (const float*)d_in[5];
    const float* mn0 = (const float*)d_in[6], *vr0 = (const float*)d_in[7];
    const float* w1 = (const float*)d_in[8],  *b1 = (const float*)d_in[9];
    const float* g1 = (const float*)d_in[10], *be1 = (const float*)d_in[11];
    const float* mn1 = (const float*)d_in[12], *vr1 = (const float*)d_in[13];
    const float* w2 = (const float*)d_in[14], *b2 = (const float*)d_in[15];
    const float* g2 = (const float*)d_in[16], *be2 = (const float*)d_in[17];
    const float* mn2 = (const float*)d_in[18], *vr2 = (const float*)d_in[19];

    char* ws = (char*)d_ws;
    float*        y0    = (float*)(ws + 0);              // 16.78 MB
    float*        y1    = (float*)(ws + 16777216);       // 8.39 MB
    float*        y2    = (float*)(ws + 25165824);       // 4.19 MB
    __bf16*       qbf   = (__bf16*)(ws + 29360128);      // 2.10 MB
    float*        qsq   = (float*)(ws + 31457280);       // 64 KB
    __bf16*       mbbf  = (__bf16*)(ws + 31522816);      // 33.55 MB
    float*        msq   = (float*)(ws + 65077248);       // 1.05 MB
    unsigned int* mind2 = (unsigned int*)(ws + 66125824);// 64 KB

    conv0_kernel<<<16384, 256, 0, stream>>>(x, w0, b0, g0, be0, mn0, vr0, y0);
    conv1_kernel<<<1024, 256, 0, stream>>>(y0, w1, b1, g1, be1, mn1, vr1, y1);
    conv2_kernel<<<1024, 256, 0, stream>>>(y1, w2, b2, g2, be2, mn2, vr2, y2);
    qnorm_kernel<<<256, 64, 0, stream>>>(y2, qbf, qsq, mind2);
    mbnorm_kernel<<<65536, 256, 0, stream>>>(mbank, mbbf, msq);
    dist_kernel<<<dim3(32, SLICES), 256, 0, stream>>>(qbf, qsq, mbbf, msq, mind2);
    finalize_kernel<<<256, 64, 0, stream>>>(mind2, (float*)d_out);
}

// Round 5
// 1351.876 us; speedup vs baseline: 3.6393x; 1.2078x over previous
//
#include <hip/hip_runtime.h>
#include <math.h>

typedef __bf16 v8bf __attribute__((ext_vector_type(8)));
typedef float  v16f __attribute__((ext_vector_type(16)));

#define EPS_BN 1e-5f
#define Q_TOTAL 16384
#define N_MEM   262144
#define SLICES  16
#define SLICE_LEN (N_MEM / SLICES)   /* 16384 */
#define CHUNK   256
#define NCHUNKS (SLICE_LEN / CHUNK)  /* 64 */

// async global->LDS, 16B/lane. LDS dest is wave-uniform base + lane*16, so
// the bank swizzle must be folded into the GLOBAL source addresses.
__device__ __forceinline__ void gload_lds16(const void* g, void* l) {
    __builtin_amdgcn_global_load_lds(
        (const __attribute__((address_space(1))) void*)g,
        (__attribute__((address_space(3))) void*)l, 16, 0, 0);
}

// ---------------------------------------------------------------------------
// conv0: [256,1,64,64] -> [256,16,32,32], 3x3 s2 p1 + BN + ReLU
__global__ void conv0_kernel(const float* __restrict__ x,
                             const float* __restrict__ w, const float* __restrict__ bias,
                             const float* __restrict__ gamma, const float* __restrict__ beta,
                             const float* __restrict__ mean, const float* __restrict__ var,
                             float* __restrict__ out) {
    int idx = blockIdx.x * 256 + threadIdx.x;
    int xo = idx & 31, yo = (idx >> 5) & 31, c = (idx >> 10) & 15, b = idx >> 14;
    const float* xp = x + (size_t)b * 4096;
    const float* wc = w + c * 9;
    float acc = 0.f;
#pragma unroll
    for (int dy = 0; dy < 3; ++dy) {
        int iy = 2 * yo + dy - 1;
        if (iy < 0) continue;
#pragma unroll
        for (int dx = 0; dx < 3; ++dx) {
            int ix = 2 * xo + dx - 1;
            if (ix < 0) continue;
            acc += wc[dy * 3 + dx] * xp[iy * 64 + ix];
        }
    }
    acc += bias[c];
    float sc = gamma[c] * rsqrtf(var[c] + EPS_BN);
    float v  = (acc - mean[c]) * sc + beta[c];
    out[idx] = fmaxf(v, 0.f);
}

// ---------------------------------------------------------------------------
// conv1: [256,16,32,32] -> [256,32,16,16]. LDS-staged per (image, 8-ch group).
__global__ void conv1_kernel(const float* __restrict__ in,
                             const float* __restrict__ w, const float* __restrict__ bias,
                             const float* __restrict__ gamma, const float* __restrict__ beta,
                             const float* __restrict__ mean, const float* __restrict__ var,
                             float* __restrict__ out) {
    __shared__ float in_s[16384];
    __shared__ float w_s[1152];
    __shared__ float sc_s[8], sh_s[8];
    int b = blockIdx.x >> 2, cg = blockIdx.x & 3;
    int t = threadIdx.x;
    const float4* ip4 = (const float4*)(in + (size_t)b * 16384);
    float4* is4 = (float4*)in_s;
    for (int i = t; i < 4096; i += 256) is4[i] = ip4[i];
    for (int i = t; i < 1152; i += 256) w_s[i] = w[cg * 1152 + i];
    if (t < 8) {
        int c = cg * 8 + t;
        float sc = gamma[c] * rsqrtf(var[c] + EPS_BN);
        sc_s[t] = sc;
        sh_s[t] = (bias[c] - mean[c]) * sc + beta[c];
    }
    __syncthreads();
    int xo = t & 15, yo = t >> 4;
    float acc[8];
#pragma unroll
    for (int c = 0; c < 8; ++c) acc[c] = 0.f;
    int iy0 = 2 * yo - 1, ix0 = 2 * xo - 1;
    for (int ci = 0; ci < 16; ++ci) {
        const float* base = in_s + ci * 1024;
        float r[9];
#pragma unroll
        for (int dy = 0; dy < 3; ++dy) {
            int iy = iy0 + dy;
            int iyc = iy < 0 ? 0 : iy;
#pragma unroll
            for (int dx = 0; dx < 3; ++dx) {
                int ix = ix0 + dx;
                int ixc = ix < 0 ? 0 : ix;
                float v = base[iyc * 32 + ixc];
                r[dy * 3 + dx] = (iy >= 0 && ix >= 0) ? v : 0.f;
            }
        }
#pragma unroll
        for (int c = 0; c < 8; ++c) {
            const float* wp = w_s + (c * 16 + ci) * 9;
#pragma unroll
            for (int k = 0; k < 9; ++k) acc[c] = fmaf(wp[k], r[k], acc[c]);
        }
    }
#pragma unroll
    for (int c = 0; c < 8; ++c) {
        float v = fmaf(acc[c], sc_s[c], sh_s[c]);
        out[((size_t)(b * 32 + cg * 8 + c) * 16 + yo) * 16 + xo] = fmaxf(v, 0.f);
    }
}

// ---------------------------------------------------------------------------
// conv2: [256,32,16,16] -> [256,64,8,8]. LDS-staged per (image, 16-ch group).
__global__ void conv2_kernel(const float* __restrict__ in,
                             const float* __restrict__ w, const float* __restrict__ bias,
                             const float* __restrict__ gamma, const float* __restrict__ beta,
                             const float* __restrict__ mean, const float* __restrict__ var,
                             float* __restrict__ out) {
    __shared__ float in_s[8192];
    __shared__ float w_s[4608];
    __shared__ float sc_s[16], sh_s[16];
    int b = blockIdx.x >> 2, cg = blockIdx.x & 3;
    int t = threadIdx.x;
    const float4* ip4 = (const float4*)(in + (size_t)b * 8192);
    float4* is4 = (float4*)in_s;
    for (int i = t; i < 2048; i += 256) is4[i] = ip4[i];
    for (int i = t; i < 4608; i += 256) w_s[i] = w[cg * 4608 + i];
    if (t < 16) {
        int c = cg * 16 + t;
        float sc = gamma[c] * rsqrtf(var[c] + EPS_BN);
        sc_s[t] = sc;
        sh_s[t] = (bias[c] - mean[c]) * sc + beta[c];
    }
    __syncthreads();
    int xo = t & 7, yo = (t >> 3) & 7, cs = t >> 6;
    float acc[4];
#pragma unroll
    for (int l = 0; l < 4; ++l) acc[l] = 0.f;
    int iy0 = 2 * yo - 1, ix0 = 2 * xo - 1;
    for (int ci = 0; ci < 32; ++ci) {
        const float* base = in_s + ci * 256;
        float r[9];
#pragma unroll
        for (int dy = 0; dy < 3; ++dy) {
            int iy = iy0 + dy;
            int iyc = iy < 0 ? 0 : iy;
#pragma unroll
            for (int dx = 0; dx < 3; ++dx) {
                int ix = ix0 + dx;
                int ixc = ix < 0 ? 0 : ix;
                float v = base[iyc * 16 + ixc];
                r[dy * 3 + dx] = (iy >= 0 && ix >= 0) ? v : 0.f;
            }
        }
#pragma unroll
        for (int l = 0; l < 4; ++l) {
            const float* wp = w_s + ((cs * 4 + l) * 32 + ci) * 9;
#pragma unroll
            for (int k = 0; k < 9; ++k) acc[l] = fmaf(wp[k], r[k], acc[l]);
        }
    }
#pragma unroll
    for (int l = 0; l < 4; ++l) {
        int c = cg * 16 + cs * 4 + l;
        float v = fmaf(acc[l], sc_s[cs * 4 + l], sh_s[cs * 4 + l]);
        out[((size_t)(b * 64 + c) * 8 + yo) * 8 + xo] = fmaxf(v, 0.f);
    }
}

// ---------------------------------------------------------------------------
// qnorm: y2 [256,64,8,8] -> transpose -> L2 normalize -> bf16; qsq from the
// bf16-rounded values. Also initializes mind2 (+inf) for the dist kernel.
__global__ void qnorm_kernel(const float* __restrict__ y2,
                             __bf16* __restrict__ q, float* __restrict__ qsq,
                             unsigned int* __restrict__ mind2) {
    __shared__ float  L1s[4096];
    __shared__ __bf16 L2s[4096];
    int b = blockIdx.x, t = threadIdx.x;          // 64 threads
    mind2[b * 64 + t] = 0x7f800000u;              // +inf init
    const float* src = y2 + (size_t)b * 4096;
    for (int i = t; i < 4096; i += 64) L1s[i] = src[i];
    __syncthreads();
    int p = t;
    float ss = 0.f;
    for (int d = 0; d < 64; ++d) { float v = L1s[d * 64 + p]; ss += v * v; }
    float inv = 1.f / fmaxf(sqrtf(ss), 1e-12f);
    float q2 = 0.f;
    for (int d = 0; d < 64; ++d) {
        float v = L1s[d * 64 + p] * inv;
        __bf16 bv = (__bf16)v;
        L2s[p * 64 + d] = bv;
        float fb = (float)bv;
        q2 += fb * fb;
    }
    qsq[b * 64 + p] = q2;
    __syncthreads();
    for (int p2 = 0; p2 < 64; ++p2)
        q[((size_t)(b * 64 + p2)) * 64 + t] = L2s[p2 * 64 + t];
}

// mbnorm: normalize bank rows, pack bf16, msq from bf16-rounded values.
__global__ void mbnorm_kernel(const float* __restrict__ mb,
                              __bf16* __restrict__ mbbf, float* __restrict__ msq) {
    int row  = blockIdx.x * 4 + (threadIdx.x >> 6);
    int lane = threadIdx.x & 63;
    float v = mb[(size_t)row * 64 + lane];
    float ss = v * v;
#pragma unroll
    for (int o = 1; o < 64; o <<= 1) ss += __shfl_xor(ss, o, 64);
    float inv = 1.f / fmaxf(sqrtf(ss), 1e-12f);
    __bf16 bv = (__bf16)(v * inv);
    mbbf[(size_t)row * 64 + lane] = bv;
    float fb = (float)bv;
    float s2 = fb * fb;
#pragma unroll
    for (int o = 1; o < 64; o <<= 1) s2 += __shfl_xor(s2, o, 64);
    if (lane == 0) msq[row] = s2;
}

// ---------------------------------------------------------------------------
// dist v5: mt=4 strips (BM=512/block), CHUNK=256 double-buffered.
// v4 spilled (VGPR 256 + AGPR, 1 wave/SIMD, 4.5 GB scratch) because the fully
// unrolled nt=8 tile loop hoisted all 8 tiles' bf[4] (128 VGPR) + interleaved
// 8 acc chains. Fix: #pragma unroll 1 on the nt loop + manual 1-deep software
// pipeline (bfc/bfn, msc/msn scalars; arrays only indexed by fully-unrolled
// inner loops -> stay in regs). nt*32 ≡ 0 mod 8 -> swizzle/offsets are
// nt-invariant; tile address = base + nt*4096 B.
// Live/lane ≈ 237: a 64 + tmax 64 + bfc 16 + bfn 16 + A0/A1 32 + addr ~25.
__global__ __launch_bounds__(256)
void dist_kernel(const __bf16* __restrict__ q, const float* __restrict__ qsq,
                 const __bf16* __restrict__ mb, const float* __restrict__ msq,
                 unsigned int* __restrict__ mind2) {
    __shared__ __align__(16) __bf16 Bs[2][CHUNK * 64];   // 2 x 32 KB
    const int t = threadIdx.x;
    const int wave = t >> 6, lane = t & 63;
    const int n32 = lane & 31, half = lane >> 5;
    const int mbase = blockIdx.x * 512 + wave * 128;
    const int slice = blockIdx.y;

    // A fragments: 4 strips x 4 ksteps, register resident (64 VGPR).
    v8bf a[4][4];
#pragma unroll
    for (int s = 0; s < 4; ++s)
#pragma unroll
        for (int ks = 0; ks < 4; ++ks)
            a[s][ks] = *(const v8bf*)(q + (size_t)(mbase + s * 32 + n32) * 64
                                        + ks * 16 + half * 8);

    float tmax[4][16];
#pragma unroll
    for (int s = 0; s < 4; ++s)
#pragma unroll
        for (int r = 0; r < 16; ++r) tmax[s][r] = -3.0e38f;

    // single staging pointer: granule g=j*256+t -> row g>>3, pos (g&7)^(row&7);
    // j*32 ≡ 0 mod 8 -> set j reads src0 + j*4096 B.
    const int r0 = t >> 3, c0 = (t & 7) ^ (r0 & 7);
    const __bf16* gp = mb + (size_t)slice * SLICE_LEN * 64 + r0 * 64 + c0 * 8;
    const int wbase = wave * 1024;

    // prologue: chunk 0 -> buf 0
#pragma unroll
    for (int j = 0; j < 8; ++j) {
        gload_lds16(gp, (char*)Bs[0] + j * 4096 + wbase);
        gp += 2048;
    }

    const float* msp = msq + slice * SLICE_LEN + n32;

    // ds_read offsets (nt-invariant: n&7 == n32&7)
    const int sw = (n32 & 7) << 4;
    int offk[4];
#pragma unroll
    for (int ks = 0; ks < 4; ++ks) offk[ks] = (((ks * 2 + half) << 4) ^ sw);

    auto step = [&](const char* bp, char* pdst, bool more) {
        __syncthreads();          // drains staging (vmcnt0) + sync
        if (more) {
#pragma unroll
            for (int j = 0; j < 8; ++j) {
                gload_lds16(gp, pdst + j * 4096 + wbase);
                gp += 2048;
            }
        }
        const char* tp = bp + n32 * 128;
        // preload tile 0
        v8bf bfc[4];
#pragma unroll
        for (int ks = 0; ks < 4; ++ks) bfc[ks] = *(const v8bf*)(tp + offk[ks]);
        float msc = msp[0];
#pragma unroll 1
        for (int nt = 0; nt < 8; ++nt) {
            v8bf bfn[4];
            float msn_v = 0.f;
            if (nt < 7) {
#pragma unroll
                for (int ks = 0; ks < 4; ++ks)
                    bfn[ks] = *(const v8bf*)(tp + (nt + 1) * 4096 + offk[ks]);
                msn_v = msp[(nt + 1) * 32];
            }
            const float cinit = -0.5f * msc;
#pragma unroll
            for (int sg = 0; sg < 2; ++sg) {
                v16f A0, A1;
#pragma unroll
                for (int r = 0; r < 16; ++r) { A0[r] = cinit; A1[r] = cinit; }
#pragma unroll
                for (int ks = 0; ks < 4; ++ks) {
                    A0 = __builtin_amdgcn_mfma_f32_32x32x16_bf16(a[2 * sg][ks],     bfc[ks], A0, 0, 0, 0);
                    A1 = __builtin_amdgcn_mfma_f32_32x32x16_bf16(a[2 * sg + 1][ks], bfc[ks], A1, 0, 0, 0);
                }
#pragma unroll
                for (int r = 0; r < 16; ++r) {
                    tmax[2 * sg][r]     = fmaxf(tmax[2 * sg][r],     A0[r]);
                    tmax[2 * sg + 1][r] = fmaxf(tmax[2 * sg + 1][r], A1[r]);
                }
            }
            if (nt < 7) {
#pragma unroll
                for (int ks = 0; ks < 4; ++ks) bfc[ks] = bfn[ks];
                msc = msn_v;
            }
        }
        msp += CHUNK;
    };

    for (int ch = 0; ch < NCHUNKS; ch += 2) {
        step((const char*)Bs[0], (char*)Bs[1], ch + 1 < NCHUNKS);
        step((const char*)Bs[1], (char*)Bs[0], ch + 2 < NCHUNKS);
    }

    // min_n(msq - 2 dot) = -2 * max_n(dot - msq/2) = -2 * tmax
#pragma unroll
    for (int s = 0; s < 4; ++s)
#pragma unroll
        for (int r = 0; r < 16; ++r) {
            float v = tmax[s][r];
            v = fmaxf(v, __shfl_xor(v, 1, 64));
            v = fmaxf(v, __shfl_xor(v, 2, 64));
            v = fmaxf(v, __shfl_xor(v, 4, 64));
            v = fmaxf(v, __shfl_xor(v, 8, 64));
            v = fmaxf(v, __shfl_xor(v, 16, 64));
            tmax[s][r] = v;
        }
    if (n32 == 0) {
#pragma unroll
        for (int s = 0; s < 4; ++s)
#pragma unroll
            for (int r = 0; r < 16; ++r) {
                int row = (r & 3) + 8 * (r >> 2) + 4 * half;  // C/D row map
                int m = mbase + s * 32 + row;
                float dd = fmaxf(qsq[m] - 2.0f * tmax[s][r], 0.f);
                atomicMin(mind2 + m, __float_as_uint(dd));
            }
    }
}

// finalize: out[b] = max_p sqrt(mind2[b*64+p])
__global__ void finalize_kernel(const unsigned int* __restrict__ mind2,
                                float* __restrict__ out) {
    int b = blockIdx.x, l = threadIdx.x;
    float v = __uint_as_float(mind2[b * 64 + l]);
    float d = sqrtf(fmaxf(v, 0.f));
#pragma unroll
    for (int o = 1; o < 64; o <<= 1) d = fmaxf(d, __shfl_xor(d, o, 64));
    if (l == 0) out[b] = d;
}

// ---------------------------------------------------------------------------
extern "C" void kernel_launch(void* const* d_in, const int* in_sizes, int n_in,
                              void* d_out, int out_size, void* d_ws, size_t ws_size,
                              hipStream_t stream) {
    (void)in_sizes; (void)n_in; (void)out_size; (void)ws_size;
    const float* x     = (const float*)d_in[0];
    const float* mbank = (const float*)d_in[1];
    const float* w0 = (const float*)d_in[2],  *b0 = (const float*)d_in[3];
    const float* g0 = (const float*)d_in[4],  *be0 = (const float*)d_in[5];
    const float* mn0 = (const float*)d_in[6], *vr0 = (const float*)d_in[7];
    const float* w1 = (const float*)d_in[8],  *b1 = (const float*)d_in[9];
    const float* g1 = (const float*)d_in[10], *be1 = (const float*)d_in[11];
    const float* mn1 = (const float*)d_in[12], *vr1 = (const float*)d_in[13];
    const float* w2 = (const float*)d_in[14], *b2 = (const float*)d_in[15];
    const float* g2 = (const float*)d_in[16], *be2 = (const float*)d_in[17];
    const float* mn2 = (const float*)d_in[18], *vr2 = (const float*)d_in[19];

    char* ws = (char*)d_ws;
    float*        y0    = (float*)(ws + 0);              // 16.78 MB
    float*        y1    = (float*)(ws + 16777216);       // 8.39 MB
    float*        y2    = (float*)(ws + 25165824);       // 4.19 MB
    __bf16*       qbf   = (__bf16*)(ws + 29360128);      // 2.10 MB
    float*        qsq   = (float*)(ws + 31457280);       // 64 KB
    __bf16*       mbbf  = (__bf16*)(ws + 31522816);      // 33.55 MB
    float*        msq   = (float*)(ws + 65077248);       // 1.05 MB
    unsigned int* mind2 = (unsigned int*)(ws + 66125824);// 64 KB

    conv0_kernel<<<16384, 256, 0, stream>>>(x, w0, b0, g0, be0, mn0, vr0, y0);
    conv1_kernel<<<1024, 256, 0, stream>>>(y0, w1, b1, g1, be1, mn1, vr1, y1);
    conv2_kernel<<<1024, 256, 0, stream>>>(y1, w2, b2, g2, be2, mn2, vr2, y2);
    qnorm_kernel<<<256, 64, 0, stream>>>(y2, qbf, qsq, mind2);
    mbnorm_kernel<<<65536, 256, 0, stream>>>(mbank, mbbf, msq);
    dist_kernel<<<dim3(32, SLICES), 256, 0, stream>>>(qbf, qsq, mbbf, msq, mind2);
    finalize_kernel<<<256, 64, 0, stream>>>(mind2, (float*)d_out);
}

// Round 6
// 734.281 us; speedup vs baseline: 6.7002x; 1.8411x over previous
//
#include <hip/hip_runtime.h>
#include <math.h>

typedef __bf16 v8bf __attribute__((ext_vector_type(8)));
typedef float  v16f __attribute__((ext_vector_type(16)));

#define EPS_BN 1e-5f
#define Q_TOTAL 16384
#define N_MEM   262144
#define SLICES  16
#define SLICE_LEN (N_MEM / SLICES)   /* 16384 */
#define CHUNK   256
#define NCHUNKS (SLICE_LEN / CHUNK)  /* 64 */

// async global->LDS, 16B/lane. LDS dest is wave-uniform base + lane*16, so
// the bank swizzle must be folded into the GLOBAL source addresses.
__device__ __forceinline__ void gload_lds16(const void* g, void* l) {
    __builtin_amdgcn_global_load_lds(
        (const __attribute__((address_space(1))) void*)g,
        (__attribute__((address_space(3))) void*)l, 16, 0, 0);
}

// ---------------------------------------------------------------------------
// conv0: [256,1,64,64] -> [256,16,32,32], 3x3 s2 p1 + BN + ReLU
__global__ void conv0_kernel(const float* __restrict__ x,
                             const float* __restrict__ w, const float* __restrict__ bias,
                             const float* __restrict__ gamma, const float* __restrict__ beta,
                             const float* __restrict__ mean, const float* __restrict__ var,
                             float* __restrict__ out) {
    int idx = blockIdx.x * 256 + threadIdx.x;
    int xo = idx & 31, yo = (idx >> 5) & 31, c = (idx >> 10) & 15, b = idx >> 14;
    const float* xp = x + (size_t)b * 4096;
    const float* wc = w + c * 9;
    float acc = 0.f;
#pragma unroll
    for (int dy = 0; dy < 3; ++dy) {
        int iy = 2 * yo + dy - 1;
        if (iy < 0) continue;
#pragma unroll
        for (int dx = 0; dx < 3; ++dx) {
            int ix = 2 * xo + dx - 1;
            if (ix < 0) continue;
            acc += wc[dy * 3 + dx] * xp[iy * 64 + ix];
        }
    }
    acc += bias[c];
    float sc = gamma[c] * rsqrtf(var[c] + EPS_BN);
    float v  = (acc - mean[c]) * sc + beta[c];
    out[idx] = fmaxf(v, 0.f);
}

// ---------------------------------------------------------------------------
// conv1: [256,16,32,32] -> [256,32,16,16]. LDS-staged per (image, 8-ch group).
__global__ void conv1_kernel(const float* __restrict__ in,
                             const float* __restrict__ w, const float* __restrict__ bias,
                             const float* __restrict__ gamma, const float* __restrict__ beta,
                             const float* __restrict__ mean, const float* __restrict__ var,
                             float* __restrict__ out) {
    __shared__ float in_s[16384];
    __shared__ float w_s[1152];
    __shared__ float sc_s[8], sh_s[8];
    int b = blockIdx.x >> 2, cg = blockIdx.x & 3;
    int t = threadIdx.x;
    const float4* ip4 = (const float4*)(in + (size_t)b * 16384);
    float4* is4 = (float4*)in_s;
    for (int i = t; i < 4096; i += 256) is4[i] = ip4[i];
    for (int i = t; i < 1152; i += 256) w_s[i] = w[cg * 1152 + i];
    if (t < 8) {
        int c = cg * 8 + t;
        float sc = gamma[c] * rsqrtf(var[c] + EPS_BN);
        sc_s[t] = sc;
        sh_s[t] = (bias[c] - mean[c]) * sc + beta[c];
    }
    __syncthreads();
    int xo = t & 15, yo = t >> 4;
    float acc[8];
#pragma unroll
    for (int c = 0; c < 8; ++c) acc[c] = 0.f;
    int iy0 = 2 * yo - 1, ix0 = 2 * xo - 1;
    for (int ci = 0; ci < 16; ++ci) {
        const float* base = in_s + ci * 1024;
        float r[9];
#pragma unroll
        for (int dy = 0; dy < 3; ++dy) {
            int iy = iy0 + dy;
            int iyc = iy < 0 ? 0 : iy;
#pragma unroll
            for (int dx = 0; dx < 3; ++dx) {
                int ix = ix0 + dx;
                int ixc = ix < 0 ? 0 : ix;
                float v = base[iyc * 32 + ixc];
                r[dy * 3 + dx] = (iy >= 0 && ix >= 0) ? v : 0.f;
            }
        }
#pragma unroll
        for (int c = 0; c < 8; ++c) {
            const float* wp = w_s + (c * 16 + ci) * 9;
#pragma unroll
            for (int k = 0; k < 9; ++k) acc[c] = fmaf(wp[k], r[k], acc[c]);
        }
    }
#pragma unroll
    for (int c = 0; c < 8; ++c) {
        float v = fmaf(acc[c], sc_s[c], sh_s[c]);
        out[((size_t)(b * 32 + cg * 8 + c) * 16 + yo) * 16 + xo] = fmaxf(v, 0.f);
    }
}

// ---------------------------------------------------------------------------
// conv2: [256,32,16,16] -> [256,64,8,8]. LDS-staged per (image, 16-ch group).
__global__ void conv2_kernel(const float* __restrict__ in,
                             const float* __restrict__ w, const float* __restrict__ bias,
                             const float* __restrict__ gamma, const float* __restrict__ beta,
                             const float* __restrict__ mean, const float* __restrict__ var,
                             float* __restrict__ out) {
    __shared__ float in_s[8192];
    __shared__ float w_s[4608];
    __shared__ float sc_s[16], sh_s[16];
    int b = blockIdx.x >> 2, cg = blockIdx.x & 3;
    int t = threadIdx.x;
    const float4* ip4 = (const float4*)(in + (size_t)b * 8192);
    float4* is4 = (float4*)in_s;
    for (int i = t; i < 2048; i += 256) is4[i] = ip4[i];
    for (int i = t; i < 4608; i += 256) w_s[i] = w[cg * 4608 + i];
    if (t < 16) {
        int c = cg * 16 + t;
        float sc = gamma[c] * rsqrtf(var[c] + EPS_BN);
        sc_s[t] = sc;
        sh_s[t] = (bias[c] - mean[c]) * sc + beta[c];
    }
    __syncthreads();
    int xo = t & 7, yo = (t >> 3) & 7, cs = t >> 6;
    float acc[4];
#pragma unroll
    for (int l = 0; l < 4; ++l) acc[l] = 0.f;
    int iy0 = 2 * yo - 1, ix0 = 2 * xo - 1;
    for (int ci = 0; ci < 32; ++ci) {
        const float* base = in_s + ci * 256;
        float r[9];
#pragma unroll
        for (int dy = 0; dy < 3; ++dy) {
            int iy = iy0 + dy;
            int iyc = iy < 0 ? 0 : iy;
#pragma unroll
            for (int dx = 0; dx < 3; ++dx) {
                int ix = ix0 + dx;
                int ixc = ix < 0 ? 0 : ix;
                float v = base[iyc * 16 + ixc];
                r[dy * 3 + dx] = (iy >= 0 && ix >= 0) ? v : 0.f;
            }
        }
#pragma unroll
        for (int l = 0; l < 4; ++l) {
            const float* wp = w_s + ((cs * 4 + l) * 32 + ci) * 9;
#pragma unroll
            for (int k = 0; k < 9; ++k) acc[l] = fmaf(wp[k], r[k], acc[l]);
        }
    }
#pragma unroll
    for (int l = 0; l < 4; ++l) {
        int c = cg * 16 + cs * 4 + l;
        float v = fmaf(acc[l], sc_s[cs * 4 + l], sh_s[cs * 4 + l]);
        out[((size_t)(b * 64 + c) * 8 + yo) * 8 + xo] = fmaxf(v, 0.f);
    }
}

// ---------------------------------------------------------------------------
// qnorm: y2 [256,64,8,8] -> transpose -> L2 normalize -> bf16; qsq from the
// bf16-rounded values. Also initializes mind2 (+inf) for the dist kernel.
__global__ void qnorm_kernel(const float* __restrict__ y2,
                             __bf16* __restrict__ q, float* __restrict__ qsq,
                             unsigned int* __restrict__ mind2) {
    __shared__ float  L1s[4096];
    __shared__ __bf16 L2s[4096];
    int b = blockIdx.x, t = threadIdx.x;          // 64 threads
    mind2[b * 64 + t] = 0x7f800000u;              // +inf init
    const float* src = y2 + (size_t)b * 4096;
    for (int i = t; i < 4096; i += 64) L1s[i] = src[i];
    __syncthreads();
    int p = t;
    float ss = 0.f;
    for (int d = 0; d < 64; ++d) { float v = L1s[d * 64 + p]; ss += v * v; }
    float inv = 1.f / fmaxf(sqrtf(ss), 1e-12f);
    float q2 = 0.f;
    for (int d = 0; d < 64; ++d) {
        float v = L1s[d * 64 + p] * inv;
        __bf16 bv = (__bf16)v;
        L2s[p * 64 + d] = bv;
        float fb = (float)bv;
        q2 += fb * fb;
    }
    qsq[b * 64 + p] = q2;
    __syncthreads();
    for (int p2 = 0; p2 < 64; ++p2)
        q[((size_t)(b * 64 + p2)) * 64 + t] = L2s[p2 * 64 + t];
}

// mbnorm: normalize bank rows, pack bf16. msq dropped: rows are unit-norm;
// msq = 1 ± ~0.004 (bf16 rounding); dist uses msq := 1 (error << threshold).
__global__ void mbnorm_kernel(const float* __restrict__ mb,
                              __bf16* __restrict__ mbbf) {
    int row  = blockIdx.x * 4 + (threadIdx.x >> 6);
    int lane = threadIdx.x & 63;
    float v = mb[(size_t)row * 64 + lane];
    float ss = v * v;
#pragma unroll
    for (int o = 1; o < 64; o <<= 1) ss += __shfl_xor(ss, o, 64);
    float inv = 1.f / fmaxf(sqrtf(ss), 1e-12f);
    mbbf[(size_t)row * 64 + lane] = (__bf16)(v * inv);
}

// ---------------------------------------------------------------------------
// dist v6: mt=2 strips (BM=256/block), CHUNK=256 double-buffered.
// v5 lesson: mt=4 (128 persistent regs + 32 in-flight AGPR) -> ~288 unified
// regs -> 1 wave/SIMD -> everything exposed (MfmaUtil 19.8%). v6 halves the
// persistent state (a 32 + tmax 32) and kills per-nt VALU:
//  - msq := 1 (rows unit-norm): no msq loads, C-operand = hoisted ZERO16,
//    d^2 = qsq + 1 - 2*max_n dot
//  - nt loop #pragma unroll 2: ping-pong bf tiles, copies rename away
// Per nt: 8 MFMA (256 pipe cyc) vs ~45 VALU instr -> MFMA-bound at >=2
// waves/SIMD. Target: ~165 regs, 2 blocks/CU (LDS 64 KB), 8 waves/CU.
__global__ __launch_bounds__(256)
void dist_kernel(const __bf16* __restrict__ q, const float* __restrict__ qsq,
                 const __bf16* __restrict__ mb,
                 unsigned int* __restrict__ mind2) {
    __shared__ __align__(16) __bf16 Bs[2][CHUNK * 64];   // 2 x 32 KB
    const int t = threadIdx.x;
    const int wave = t >> 6, lane = t & 63;
    const int n32 = lane & 31, half = lane >> 5;
    const int mbase = blockIdx.x * 256 + wave * 64;
    const int slice = blockIdx.y;

    // A fragments: 2 strips x 4 ksteps (32 VGPR).
    v8bf a[2][4];
#pragma unroll
    for (int s = 0; s < 2; ++s)
#pragma unroll
        for (int ks = 0; ks < 4; ++ks)
            a[s][ks] = *(const v8bf*)(q + (size_t)(mbase + s * 32 + n32) * 64
                                        + ks * 16 + half * 8);

    float tmax[2][16];
#pragma unroll
    for (int s = 0; s < 2; ++s)
#pragma unroll
        for (int r = 0; r < 16; ++r) tmax[s][r] = -3.0e38f;

    v16f Z;                       // hoisted zero C-operand (16 regs, read-only)
#pragma unroll
    for (int r = 0; r < 16; ++r) Z[r] = 0.f;

    // single staging pointer: granule g=j*256+t -> row g>>3, pos (g&7)^(row&7);
    // j*32 ≡ 0 mod 8 -> set j reads src0 + j*4096 B.
    const int r0 = t >> 3, c0 = (t & 7) ^ (r0 & 7);
    const __bf16* gp = mb + (size_t)slice * SLICE_LEN * 64 + r0 * 64 + c0 * 8;
    const int wbase = wave * 1024;

    // prologue: chunk 0 -> buf 0
#pragma unroll
    for (int j = 0; j < 8; ++j) {
        gload_lds16(gp, (char*)Bs[0] + j * 4096 + wbase);
        gp += 2048;
    }

    // ds_read offsets (nt-invariant: n&7 == n32&7)
    const int sw = (n32 & 7) << 4;
    int offk[4];
#pragma unroll
    for (int ks = 0; ks < 4; ++ks) offk[ks] = (((ks * 2 + half) << 4) ^ sw);

    auto step = [&](const char* bp, char* pdst, bool more) {
        __syncthreads();          // drains staging (vmcnt0) + sync
        if (more) {
#pragma unroll
            for (int j = 0; j < 8; ++j) {
                gload_lds16(gp, pdst + j * 4096 + wbase);
                gp += 2048;
            }
        }
        const char* tp = bp + n32 * 128;
        v8bf bfc[4];
#pragma unroll
        for (int ks = 0; ks < 4; ++ks) bfc[ks] = *(const v8bf*)(tp + offk[ks]);
#pragma unroll 2
        for (int nt = 0; nt < 8; ++nt) {
            v8bf bfn[4];
            if (nt < 7) {
#pragma unroll
                for (int ks = 0; ks < 4; ++ks)
                    bfn[ks] = *(const v8bf*)(tp + (nt + 1) * 4096 + offk[ks]);
            }
            v16f A0 = __builtin_amdgcn_mfma_f32_32x32x16_bf16(a[0][0], bfc[0], Z, 0, 0, 0);
            v16f A1 = __builtin_amdgcn_mfma_f32_32x32x16_bf16(a[1][0], bfc[0], Z, 0, 0, 0);
#pragma unroll
            for (int ks = 1; ks < 4; ++ks) {
                A0 = __builtin_amdgcn_mfma_f32_32x32x16_bf16(a[0][ks], bfc[ks], A0, 0, 0, 0);
                A1 = __builtin_amdgcn_mfma_f32_32x32x16_bf16(a[1][ks], bfc[ks], A1, 0, 0, 0);
            }
#pragma unroll
            for (int r = 0; r < 16; ++r) {
                tmax[0][r] = fmaxf(tmax[0][r], A0[r]);
                tmax[1][r] = fmaxf(tmax[1][r], A1[r]);
            }
            if (nt < 7) {
#pragma unroll
                for (int ks = 0; ks < 4; ++ks) bfc[ks] = bfn[ks];
            }
        }
    };

    for (int ch = 0; ch < NCHUNKS; ch += 2) {
        step((const char*)Bs[0], (char*)Bs[1], ch + 1 < NCHUNKS);
        step((const char*)Bs[1], (char*)Bs[0], ch + 2 < NCHUNKS);
    }

    // cross-lane max over the 32 columns
#pragma unroll
    for (int s = 0; s < 2; ++s)
#pragma unroll
        for (int r = 0; r < 16; ++r) {
            float v = tmax[s][r];
            v = fmaxf(v, __shfl_xor(v, 1, 64));
            v = fmaxf(v, __shfl_xor(v, 2, 64));
            v = fmaxf(v, __shfl_xor(v, 4, 64));
            v = fmaxf(v, __shfl_xor(v, 8, 64));
            v = fmaxf(v, __shfl_xor(v, 16, 64));
            tmax[s][r] = v;
        }
    if (n32 == 0) {
#pragma unroll
        for (int s = 0; s < 2; ++s)
#pragma unroll
            for (int r = 0; r < 16; ++r) {
                int row = (r & 3) + 8 * (r >> 2) + 4 * half;  // C/D row map
                int m = mbase + s * 32 + row;
                // d^2 = qsq + |m|^2 - 2 dot, with |m|^2 := 1 (unit rows)
                float dd = fmaxf(qsq[m] + 1.0f - 2.0f * tmax[s][r], 0.f);
                atomicMin(mind2 + m, __float_as_uint(dd));
            }
    }
}

// finalize: out[b] = max_p sqrt(mind2[b*64+p])
__global__ void finalize_kernel(const unsigned int* __restrict__ mind2,
                                float* __restrict__ out) {
    int b = blockIdx.x, l = threadIdx.x;
    float v = __uint_as_float(mind2[b * 64 + l]);
    float d = sqrtf(fmaxf(v, 0.f));
#pragma unroll
    for (int o = 1; o < 64; o <<= 1) d = fmaxf(d, __shfl_xor(d, o, 64));
    if (l == 0) out[b] = d;
}

// ---------------------------------------------------------------------------
extern "C" void kernel_launch(void* const* d_in, const int* in_sizes, int n_in,
                              void* d_out, int out_size, void* d_ws, size_t ws_size,
                              hipStream_t stream) {
    (void)in_sizes; (void)n_in; (void)out_size; (void)ws_size;
    const float* x     = (const float*)d_in[0];
    const float* mbank = (const float*)d_in[1];
    const float* w0 = (const float*)d_in[2],  *b0 = (const float*)d_in[3];
    const float* g0 = (const float*)d_in[4],  *be0 = (const float*)d_in[5];
    const float* mn0 = (const float*)d_in[6], *vr0 = (const float*)d_in[7];
    const float* w1 = (const float*)d_in[8],  *b1 = (const float*)d_in[9];
    const float* g1 = (const float*)d_in[10], *be1 = (const float*)d_in[11];
    const float* mn1 = (const float*)d_in[12], *vr1 = (const float*)d_in[13];
    const float* w2 = (const float*)d_in[14], *b2 = (const float*)d_in[15];
    const float* g2 = (const float*)d_in[16], *be2 = (const float*)d_in[17];
    const float* mn2 = (const float*)d_in[18], *vr2 = (const float*)d_in[19];

    char* ws = (char*)d_ws;
    float*        y0    = (float*)(ws + 0);              // 16.78 MB
    float*        y1    = (float*)(ws + 16777216);       // 8.39 MB
    float*        y2    = (float*)(ws + 25165824);       // 4.19 MB
    __bf16*       qbf   = (__bf16*)(ws + 29360128);      // 2.10 MB
    float*        qsq   = (float*)(ws + 31457280);       // 64 KB
    __bf16*       mbbf  = (__bf16*)(ws + 31522816);      // 33.55 MB
    unsigned int* mind2 = (unsigned int*)(ws + 66125824);// 64 KB

    conv0_kernel<<<16384, 256, 0, stream>>>(x, w0, b0, g0, be0, mn0, vr0, y0);
    conv1_kernel<<<1024, 256, 0, stream>>>(y0, w1, b1, g1, be1, mn1, vr1, y1);
    conv2_kernel<<<1024, 256, 0, stream>>>(y1, w2, b2, g2, be2, mn2, vr2, y2);
    qnorm_kernel<<<256, 64, 0, stream>>>(y2, qbf, qsq, mind2);
    mbnorm_kernel<<<65536, 256, 0, stream>>>(mbank, mbbf);
    dist_kernel<<<dim3(64, SLICES), 256, 0, stream>>>(qbf, qsq, mbbf, mind2);
    finalize_kernel<<<256, 64, 0, stream>>>(mind2, (float*)d_out);
}